// Round 1
// baseline (1932.038 us; speedup 1.0000x reference)
//
#include <hip/hip_runtime.h>

// Problem constants
#define C_    512
#define H_    8
#define NSEQ  64
#define XS    520   // sh_x row stride (bf16 elems): 512 + 8 pad, rows 1040B (16B-aligned)
#define KS    72    // k/q/v/w buffer row stride (bf16 elems), rows 144B
#define SS    68    // S buffer row stride (f32 elems), rows 272B

#define SM_XBYTES (64 * XS * 2)                 // 66560
#define SM_GRP    (9216 + 9216 + 64 * SS * 4)   // kbuf + qbuf + sbuf = 35840
#define SM_MROW   (SM_XBYTES + 2 * SM_GRP)      // 138240
#define SM_TOTAL  (SM_MROW + 256)               // 138496 bytes < 160 KiB

typedef __attribute__((ext_vector_type(4))) float f32x4;
typedef __attribute__((ext_vector_type(8))) short bf16x8;
typedef __attribute__((ext_vector_type(4))) short s16x4;

__device__ __forceinline__ short f2b(float f) {
  union { float f; unsigned u; } v; v.f = f;
  return (short)((v.u + 0x7fffu + ((v.u >> 16) & 1u)) >> 16);   // RNE
}

__device__ __forceinline__ f32x4 mfma16(bf16x8 a, bf16x8 b, f32x4 c) {
  return __builtin_amdgcn_mfma_f32_16x16x32_bf16(a, b, c, 0, 0, 0);
}

// One 32x32 quadrant of a per-head projection: out[d][n] = sum_c W[8d+h][c] * x[c][n] + bias
// TRANS=1: store transposed obuf[n][d] (for K,Q). TRANS=0: store normal obuf[d][n] (for V).
template <int TRANS>
__device__ __forceinline__ void proj_head(
    const short* __restrict__ W, const float* __restrict__ bias,
    const short* sh_x, short* obuf, int h, int m0, int n0, int l16, int g4)
{
  f32x4 acc[2][2] = {};
  const short* w0 = W + (size_t)(8 * (m0 + l16) + h) * C_;
  const short* w1 = W + (size_t)(8 * (m0 + 16 + l16) + h) * C_;
  const short* x0 = sh_x + (n0 + l16) * XS;
  const short* x1 = sh_x + (n0 + 16 + l16) * XS;
#pragma unroll 4
  for (int kk = 0; kk < C_; kk += 32) {
    const int ko = kk + 8 * g4;
    bf16x8 a0 = *(const bf16x8*)(w0 + ko);
    bf16x8 a1 = *(const bf16x8*)(w1 + ko);
    bf16x8 b0 = *(const bf16x8*)(x0 + ko);
    bf16x8 b1 = *(const bf16x8*)(x1 + ko);
    acc[0][0] = mfma16(a0, b0, acc[0][0]);
    acc[0][1] = mfma16(a0, b1, acc[0][1]);
    acc[1][0] = mfma16(a1, b0, acc[1][0]);
    acc[1][1] = mfma16(a1, b1, acc[1][1]);
  }
#pragma unroll
  for (int mi = 0; mi < 2; ++mi) {
    const int db = m0 + mi * 16 + 4 * g4;   // output-channel base for this acc row group
    float bs[4];
#pragma unroll
    for (int r = 0; r < 4; ++r) bs[r] = bias[8 * (db + r) + h];
#pragma unroll
    for (int ni = 0; ni < 2; ++ni) {
      if (TRANS) {
        s16x4 pk;
#pragma unroll
        for (int r = 0; r < 4; ++r) pk[r] = f2b(acc[mi][ni][r] + bs[r]);
        *(s16x4*)(obuf + (n0 + ni * 16 + l16) * KS + db) = pk;   // 8B-aligned
      } else {
#pragma unroll
        for (int r = 0; r < 4; ++r)
          obuf[(db + r) * KS + (n0 + ni * 16 + l16)] = f2b(acc[mi][ni][r] + bs[r]);
      }
    }
  }
}

// PASS=0: column attention, WG=(b, r): x_local[ch][n] = x[b,ch,r,n]   (n contiguous)
// PASS=1: row attention,    WG=(b, c): x_local[ch][n] = x[b,ch,n,c]   (n stride 64)
template <int PASS>
__global__ __launch_bounds__(512, 2)
void attn_pass(const float* __restrict__ xin, float* __restrict__ xout,
               const short* __restrict__ Wk, const short* __restrict__ Wq,
               const short* __restrict__ Wv,
               const float* __restrict__ bk, const float* __restrict__ bq,
               const float* __restrict__ bv,
               const float* __restrict__ masks)
{
  extern __shared__ char smem[];
  short* sh_x = (short*)smem;               // x transposed: sh_x[n*XS + ch], bf16
  float* mrow = (float*)(smem + SM_MROW);   // mask penalties per key

  int bid = blockIdx.x;
  if (PASS == 1) bid = (bid & 7) * 64 + (bid >> 3);  // chunk per XCD: shared lines stay local
  const int b  = bid >> 6;
  const int rc = bid & 63;
  const size_t base = (size_t)b * (C_ * 64 * 64);

  const int t = threadIdx.x;

  if (PASS == 0) {
    int ch = t >> 4;
    const int n4 = (t & 15) * 4;
#pragma unroll
    for (int it = 0; it < 16; ++it, ch += 32) {
      float4 v = *(const float4*)(xin + base + (size_t)ch * 4096 + rc * 64 + n4);
      sh_x[(n4 + 0) * XS + ch] = f2b(v.x);
      sh_x[(n4 + 1) * XS + ch] = f2b(v.y);
      sh_x[(n4 + 2) * XS + ch] = f2b(v.z);
      sh_x[(n4 + 3) * XS + ch] = f2b(v.w);
    }
  } else {
    const int n = t & 63;
    const int ch0 = (t >> 6) * 64;
    const float* src = xin + base + n * 64 + rc;
#pragma unroll 8
    for (int k = 0; k < 64; ++k) {
      const int ch = ch0 + k;
      sh_x[n * XS + ch] = f2b(src[(size_t)ch * 4096]);
    }
  }
  if (t < 64) {
    const float m = (PASS == 0) ? masks[b * 4096 + rc * 64 + t]
                                : masks[b * 4096 + t * 64 + rc];
    mrow[t] = (1.0f - m) * 1e8f;
  }
  __syncthreads();

  const int wv   = t >> 6;      // wave 0..7
  const int g    = wv >> 2;     // head-group 0/1
  const int wg   = wv & 3;      // wave in group -> quadrant
  const int lane = t & 63;
  const int l16  = lane & 15;
  const int g4   = lane >> 4;
  const int m0   = (wg >> 1) * 32;
  const int n0   = (wg & 1) * 32;

  char*  gb   = smem + SM_XBYTES + g * SM_GRP;
  short* kbuf = (short*)gb;            // khT[n][d], later aliased as wT[qq][kk]
  short* qbuf = (short*)(gb + 9216);   // qhT[n][d], later aliased as V[d][kk]
  float* sbuf = (float*)(gb + 18432);  // S_T[qq][kk] f32

  for (int hi = 0; hi < 4; ++hi) {
    const int h = hi * 2 + g;

    // P1: K, Q projections (transposed store)
    proj_head<1>(Wk, bk, sh_x, kbuf, h, m0, n0, l16, g4);
    proj_head<1>(Wq, bq, sh_x, qbuf, h, m0, n0, l16, g4);
    __syncthreads();

    // P2: S_T[qq][kk] = sum_d Q[d][qq] * K[d][kk]
    {
      f32x4 acc[2][2] = {};
      const short* q0 = qbuf + (m0 + l16) * KS;
      const short* q1 = qbuf + (m0 + 16 + l16) * KS;
      const short* k0 = kbuf + (n0 + l16) * KS;
      const short* k1 = kbuf + (n0 + 16 + l16) * KS;
#pragma unroll
      for (int d0 = 0; d0 < 64; d0 += 32) {
        const int ko = d0 + 8 * g4;
        bf16x8 a0 = *(const bf16x8*)(q0 + ko);
        bf16x8 a1 = *(const bf16x8*)(q1 + ko);
        bf16x8 b0 = *(const bf16x8*)(k0 + ko);
        bf16x8 b1 = *(const bf16x8*)(k1 + ko);
        acc[0][0] = mfma16(a0, b0, acc[0][0]);
        acc[0][1] = mfma16(a0, b1, acc[0][1]);
        acc[1][0] = mfma16(a1, b0, acc[1][0]);
        acc[1][1] = mfma16(a1, b1, acc[1][1]);
      }
#pragma unroll
      for (int mi = 0; mi < 2; ++mi)
#pragma unroll
        for (int ni = 0; ni < 2; ++ni)
#pragma unroll
          for (int r = 0; r < 4; ++r)
            sbuf[(m0 + mi * 16 + 4 * g4 + r) * SS + n0 + ni * 16 + l16] = acc[mi][ni][r];
    }
    __syncthreads();

    // P3: softmax over kk per row qq (4 lanes/row, 16 elems/lane) -> wT (bf16) into kbuf
    {
      const int tq  = t & 255;
      const int row = tq >> 2;
      const int i4  = tq & 3;
      const float* sr = sbuf + row * SS + i4 * 16;
      float v[16];
      float mx = -3.0e38f;
#pragma unroll
      for (int j = 0; j < 16; ++j) {
        const float x = sr[j] * 0.044194173824159216f - mrow[i4 * 16 + j];
        v[j] = x; mx = fmaxf(mx, x);
      }
      mx = fmaxf(mx, __shfl_xor(mx, 1));
      mx = fmaxf(mx, __shfl_xor(mx, 2));
      float s = 0.f;
#pragma unroll
      for (int j = 0; j < 16; ++j) { v[j] = __expf(v[j] - mx); s += v[j]; }
      s += __shfl_xor(s, 1);
      s += __shfl_xor(s, 2);
      const float inv = 1.0f / s;
      bf16x8 o0, o1;
#pragma unroll
      for (int j = 0; j < 8; ++j) { o0[j] = f2b(v[j] * inv); o1[j] = f2b(v[8 + j] * inv); }
      *(bf16x8*)(kbuf + row * KS + i4 * 16)     = o0;
      *(bf16x8*)(kbuf + row * KS + i4 * 16 + 8) = o1;
    }

    // P4: V projection (normal layout) into qbuf
    proj_head<0>(Wv, bv, sh_x, qbuf, h, m0, n0, l16, g4);
    __syncthreads();

    // P5: O[d][qq] = sum_kk V[d][kk] * w[kk][qq]; epilogue: out = O + x (fp32 residual)
    {
      f32x4 acc[2][2] = {};
      const short* v0 = qbuf + (m0 + l16) * KS;
      const short* v1 = qbuf + (m0 + 16 + l16) * KS;
      const short* w0 = kbuf + (n0 + l16) * KS;
      const short* w1 = kbuf + (n0 + 16 + l16) * KS;
#pragma unroll
      for (int d0 = 0; d0 < 64; d0 += 32) {
        const int ko = d0 + 8 * g4;
        bf16x8 a0 = *(const bf16x8*)(v0 + ko);
        bf16x8 a1 = *(const bf16x8*)(v1 + ko);
        bf16x8 b0 = *(const bf16x8*)(w0 + ko);
        bf16x8 b1 = *(const bf16x8*)(w1 + ko);
        acc[0][0] = mfma16(a0, b0, acc[0][0]);
        acc[0][1] = mfma16(a0, b1, acc[0][1]);
        acc[1][0] = mfma16(a1, b0, acc[1][0]);
        acc[1][1] = mfma16(a1, b1, acc[1][1]);
      }
#pragma unroll
      for (int mi = 0; mi < 2; ++mi) {
        const int db = m0 + mi * 16 + 4 * g4;
#pragma unroll
        for (int ni = 0; ni < 2; ++ni) {
          const int q = n0 + ni * 16 + l16;
#pragma unroll
          for (int r = 0; r < 4; ++r) {
            const int ch = 8 * (db + r) + h;
            const size_t off = (PASS == 0)
                ? base + (size_t)ch * 4096 + rc * 64 + q
                : base + (size_t)ch * 4096 + q * 64 + rc;
            xout[off] = acc[mi][ni][r] + xin[off];
          }
        }
      }
    }
    __syncthreads();   // before next head's P1 overwrites kbuf/qbuf
  }
}

// Convert the 6 weight tensors (each [3][512][512] f32) to bf16 in workspace.
__global__ void conv_w(const float* __restrict__ w0, const float* __restrict__ w1,
                       const float* __restrict__ w2, const float* __restrict__ w3,
                       const float* __restrict__ w4, const float* __restrict__ w5,
                       short* __restrict__ dst)
{
  const float* s;
  switch (blockIdx.y) {
    case 0: s = w0; break; case 1: s = w1; break; case 2: s = w2; break;
    case 3: s = w3; break; case 4: s = w4; break; default: s = w5; break;
  }
  const size_t off = ((size_t)blockIdx.x * 256 + threadIdx.x) * 4;
  const float4 v = *(const float4*)(s + off);
  s16x4 p = { f2b(v.x), f2b(v.y), f2b(v.z), f2b(v.w) };
  *(s16x4*)(dst + (size_t)blockIdx.y * 786432 + off) = p;
}

__global__ void copy_masks(const float* __restrict__ m, float* __restrict__ o) {
  const int i = blockIdx.x * 256 + threadIdx.x;
  ((float4*)o)[i] = ((const float4*)m)[i];
}

extern "C" void kernel_launch(void* const* d_in, const int* in_sizes, int n_in,
                              void* d_out, int out_size, void* d_ws, size_t ws_size,
                              hipStream_t stream)
{
  const float* x0    = (const float*)d_in[0];
  const float* masks = (const float*)d_in[1];
  short* wbf  = (short*)d_ws;            // [6][3][512][512] bf16
  float* xbuf = (float*)d_out;           // x lives in d_out across layers (in-place safe)
  float* mout = xbuf + 16777216;

  conv_w<<<dim3(768, 6), 256, 0, stream>>>(
      (const float*)d_in[2], (const float*)d_in[3], (const float*)d_in[4],
      (const float*)d_in[5], (const float*)d_in[6], (const float*)d_in[7], wbf);
  copy_masks<<<32, 256, 0, stream>>>(masks, mout);

  const size_t WPL = 512 * 512;   // per-layer stride within one weight tensor
  const size_t WPN = 3 * WPL;     // per-name stride
  for (int l = 0; l < 3; ++l) {
    attn_pass<0><<<512, 512, SM_TOTAL, stream>>>(
        (l == 0 ? x0 : xbuf), xbuf,
        wbf + 0 * WPN + l * WPL, wbf + 1 * WPN + l * WPL, wbf + 2 * WPN + l * WPL,
        (const float*)d_in[8] + l * 512, (const float*)d_in[9] + l * 512,
        (const float*)d_in[10] + l * 512, masks);
    attn_pass<1><<<512, 512, SM_TOTAL, stream>>>(
        xbuf, xbuf,
        wbf + 3 * WPN + l * WPL, wbf + 4 * WPN + l * WPL, wbf + 5 * WPN + l * WPL,
        (const float*)d_in[11] + l * 512, (const float*)d_in[12] + l * 512,
        (const float*)d_in[13] + l * 512, masks);
  }
}

// Round 2
// 1145.684 us; speedup vs baseline: 1.6864x; 1.6864x over previous
//
#include <hip/hip_runtime.h>

#define XS    520   // sh_x row stride (bf16): 512 + 8 pad, rows 1040B
#define KS    72    // k/q/v/w buffer row stride (bf16), rows 144B (16B-mult)

#define SM_X     (64 * XS * 2)          // 66560
#define SM_GRP   (4 * 64 * KS * 2)      // kbuf+qbuf+vbuf+wbuf = 36864
#define SM_MROW  (SM_X + 2 * SM_GRP)    // 140288
#define SM_TOTAL (SM_MROW + 256)        // 140544 < 160 KiB

typedef __attribute__((ext_vector_type(4))) float f32x4;
typedef __attribute__((ext_vector_type(8))) short bf16x8;
typedef __attribute__((ext_vector_type(4))) short s16x4;

__device__ __forceinline__ short f2b(float f) {
  union { float f; unsigned u; } v; v.f = f;
  return (short)((v.u + 0x7fffu + ((v.u >> 16) & 1u)) >> 16);   // RNE
}
__device__ __forceinline__ f32x4 mfma16(bf16x8 a, bf16x8 b, f32x4 c) {
  return __builtin_amdgcn_mfma_f32_16x16x32_bf16(a, b, c, 0, 0, 0);
}

// Packed-weight projection quadrant: out[d][n], d in [m0,m0+32), n in [n0,n0+32).
// Wp layout per head: [mh(2)][kk(16)][frag(2)][lane(64)][8] -> each wave k-step load
// is one contiguous 1KB block. TRANS=1: store obuf[n][d]; TRANS=0: obuf[d][n].
template <int TRANS>
__device__ __forceinline__ void proj_q(
    const short* __restrict__ Wp, const float* __restrict__ bp,
    const short* sh_x, short* obuf, int m0, int n0, int lane, int l16, int g4)
{
  f32x4 acc[2][2] = {};
  const short* wb = Wp + (m0 >> 5) * 16384 + lane * 8;
  const short* x0 = sh_x + (n0 + l16) * XS;
  const short* x1 = sh_x + (n0 + 16 + l16) * XS;
#pragma unroll 4
  for (int kk = 0; kk < 16; ++kk) {
    bf16x8 a0 = *(const bf16x8*)(wb + kk * 1024);
    bf16x8 a1 = *(const bf16x8*)(wb + kk * 1024 + 512);
    const int ko = kk * 32 + 8 * g4;
    bf16x8 b0 = *(const bf16x8*)(x0 + ko);
    bf16x8 b1 = *(const bf16x8*)(x1 + ko);
    acc[0][0] = mfma16(a0, b0, acc[0][0]);
    acc[0][1] = mfma16(a0, b1, acc[0][1]);
    acc[1][0] = mfma16(a1, b0, acc[1][0]);
    acc[1][1] = mfma16(a1, b1, acc[1][1]);
  }
#pragma unroll
  for (int mi = 0; mi < 2; ++mi) {
    const int db = m0 + mi * 16 + 4 * g4;
    const float4 bs = *(const float4*)(bp + db);      // db % 4 == 0, broadcast
    const float bsa[4] = { bs.x, bs.y, bs.z, bs.w };
#pragma unroll
    for (int ni = 0; ni < 2; ++ni) {
      if (TRANS) {
        s16x4 pk;
#pragma unroll
        for (int r = 0; r < 4; ++r) pk[r] = f2b(acc[mi][ni][r] + bsa[r]);
        *(s16x4*)(obuf + (n0 + ni * 16 + l16) * KS + db) = pk;
      } else {
#pragma unroll
        for (int r = 0; r < 4; ++r)
          obuf[(db + r) * KS + (n0 + ni * 16 + l16)] = f2b(acc[mi][ni][r] + bsa[r]);
      }
    }
  }
}

// PASS=0: column attention, WG=(b, r): x_local[ch][n] = x[b,ch,r,n]
// PASS=1: row attention,    WG=(b, c): x_local[ch][n] = x[b,ch,n,c]
template <int PASS>
__global__ __launch_bounds__(1024, 4)
void attn_pass(const float* __restrict__ xin, float* __restrict__ xout,
               const short* __restrict__ Wk, const short* __restrict__ Wq,
               const short* __restrict__ Wv,
               const float* __restrict__ bk, const float* __restrict__ bq,
               const float* __restrict__ bv,
               const float* __restrict__ masks)
{
  extern __shared__ char smem[];
  short* sh_x = (short*)smem;
  float* mrow = (float*)(smem + SM_MROW);

  int bid = blockIdx.x;
  if (PASS == 1) bid = (bid & 7) * 64 + (bid >> 3);   // XCD-chunked for L2 locality
  const int b  = bid >> 6;
  const int rc = bid & 63;
  const size_t base = (size_t)b * (512 * 64 * 64);

  const int t = threadIdx.x;

  if (PASS == 0) {
    const int n4 = (t & 15) * 4;
    int ch = t >> 4;                    // 0..63
#pragma unroll
    for (int it = 0; it < 8; ++it, ch += 64) {
      float4 v = *(const float4*)(xin + base + (size_t)ch * 4096 + rc * 64 + n4);
      sh_x[(n4 + 0) * XS + ch] = f2b(v.x);
      sh_x[(n4 + 1) * XS + ch] = f2b(v.y);
      sh_x[(n4 + 2) * XS + ch] = f2b(v.z);
      sh_x[(n4 + 3) * XS + ch] = f2b(v.w);
    }
  } else {
    const int n = t & 63;
    const int ch0 = (t >> 6) * 32;
    const float* src = xin + base + n * 64 + rc;
#pragma unroll 8
    for (int k = 0; k < 32; ++k) {
      const int ch = ch0 + k;
      sh_x[n * XS + ch] = f2b(src[(size_t)ch * 4096]);
    }
  }
  if (t < 64) {
    const float m = (PASS == 0) ? masks[b * 4096 + rc * 64 + t]
                                : masks[b * 4096 + t * 64 + rc];
    mrow[t] = (1.0f - m) * 1e8f;
  }
  __syncthreads();

  const int wv   = t >> 6;
  const int g    = wv >> 3;       // head-group 0/1 (8 waves each)
  const int sub  = wv & 7;
  const int lane = t & 63;
  const int l16  = lane & 15;
  const int g4   = lane >> 4;

  char* gb = smem + SM_X + g * SM_GRP;
  short* kbuf = (short*)gb;             // khT[n][d]
  short* qbuf = (short*)(gb + 9216);    // qhT[n][d]
  short* vbuf = (short*)(gb + 18432);   // V[d][n]
  short* wbuf = (short*)(gb + 27648);   // w[q][kk]

  for (int hi = 0; hi < 4; ++hi) {
    const int h = hi * 2 + g;

    // P1: K projection (subs 0-3) || Q projection (subs 4-7)
    if (sub < 4) {
      proj_q<1>(Wk + h * 32768, bk + h * 64, sh_x, kbuf,
                (sub >> 1) * 32, (sub & 1) * 32, lane, l16, g4);
    } else {
      const int s2 = sub - 4;
      proj_q<1>(Wq + h * 32768, bq + h * 64, sh_x, qbuf,
                (s2 >> 1) * 32, (s2 & 1) * 32, lane, l16, g4);
    }
    __syncthreads();

    // P2: S + in-register softmax (subs 0-3, 16 q-rows each) || V proj (subs 4-7)
    if (sub < 4) {
      const int qb = sub * 16;
      f32x4 st[4] = {};
      const short* qa = qbuf + (qb + l16) * KS;
#pragma unroll
      for (int dk = 0; dk < 2; ++dk) {
        const int ko = dk * 32 + 8 * g4;
        bf16x8 a = *(const bf16x8*)(qa + ko);
#pragma unroll
        for (int tt = 0; tt < 4; ++tt) {
          bf16x8 bb = *(const bf16x8*)(kbuf + (tt * 16 + l16) * KS + ko);
          st[tt] = mfma16(a, bb, st[tt]);   // st[tt][r] = S[q=qb+4g4+r][kk=16tt+l16]
        }
      }
      const float scale = 0.044194173824159216f;   // 1/sqrt(512)
      float v[4][4], mx[4], sm[4];
#pragma unroll
      for (int tt = 0; tt < 4; ++tt) {
        const float pen = mrow[tt * 16 + l16];
#pragma unroll
        for (int r = 0; r < 4; ++r) v[tt][r] = st[tt][r] * scale - pen;
      }
#pragma unroll
      for (int r = 0; r < 4; ++r)
        mx[r] = fmaxf(fmaxf(v[0][r], v[1][r]), fmaxf(v[2][r], v[3][r]));
#pragma unroll
      for (int d = 1; d <= 8; d <<= 1)
#pragma unroll
        for (int r = 0; r < 4; ++r) mx[r] = fmaxf(mx[r], __shfl_xor(mx[r], d));
#pragma unroll
      for (int r = 0; r < 4; ++r) sm[r] = 0.f;
#pragma unroll
      for (int tt = 0; tt < 4; ++tt)
#pragma unroll
        for (int r = 0; r < 4; ++r) { v[tt][r] = __expf(v[tt][r] - mx[r]); sm[r] += v[tt][r]; }
#pragma unroll
      for (int d = 1; d <= 8; d <<= 1)
#pragma unroll
        for (int r = 0; r < 4; ++r) sm[r] += __shfl_xor(sm[r], d);
#pragma unroll
      for (int r = 0; r < 4; ++r) sm[r] = 1.0f / sm[r];
#pragma unroll
      for (int tt = 0; tt < 4; ++tt)
#pragma unroll
        for (int r = 0; r < 4; ++r)
          wbuf[(qb + 4 * g4 + r) * KS + tt * 16 + l16] = f2b(v[tt][r] * sm[r]);
    } else {
      const int s2 = sub - 4;
      proj_q<0>(Wv + h * 32768, bv + h * 64, sh_x, vbuf,
                (s2 >> 1) * 32, (s2 & 1) * 32, lane, l16, g4);
    }
    __syncthreads();

    // P3: O[d][q] = sum_kk V[d][kk] * w[q][kk]^T  (8 waves: 16d x 32q each) + residual
    {
      const int dc = sub >> 1;
      const int qh = sub & 1;
      f32x4 oc[2] = {};
      const short* va = vbuf + (dc * 16 + l16) * KS;
#pragma unroll
      for (int dk = 0; dk < 2; ++dk) {
        const int ko = dk * 32 + 8 * g4;
        bf16x8 a = *(const bf16x8*)(va + ko);
#pragma unroll
        for (int ni = 0; ni < 2; ++ni) {
          bf16x8 bb = *(const bf16x8*)(wbuf + (qh * 32 + ni * 16 + l16) * KS + ko);
          oc[ni] = mfma16(a, bb, oc[ni]);
        }
      }
#pragma unroll
      for (int ni = 0; ni < 2; ++ni) {
        const int q = qh * 32 + ni * 16 + l16;
#pragma unroll
        for (int r = 0; r < 4; ++r) {
          const int d  = dc * 16 + 4 * g4 + r;
          const int ch = 8 * d + h;
          const size_t off = (PASS == 0)
              ? base + (size_t)ch * 4096 + rc * 64 + q
              : base + (size_t)ch * 4096 + q * 64 + rc;
          xout[off] = oc[ni][r] + xin[off];
        }
      }
    }
    __syncthreads();
  }
}

// Pack 6 weight tensors [3][512][512] f32 -> MFMA-fragment-ordered bf16:
// dst[(name*3+l)*262144 + ((((h*2+mh)*16+kk)*2+f)*64+lane)*8 + j]
//   = W[l][8*(mh*32+f*16+(lane&15))+h][kk*32+8*(lane>>4)+j]
__global__ void pack_w(const float* __restrict__ w0, const float* __restrict__ w1,
                       const float* __restrict__ w2, const float* __restrict__ w3,
                       const float* __restrict__ w4, const float* __restrict__ w5,
                       short* __restrict__ dst)
{
  const float* s;
  switch (blockIdx.y) {
    case 0: s = w0; break; case 1: s = w1; break; case 2: s = w2; break;
    case 3: s = w3; break; case 4: s = w4; break; default: s = w5; break;
  }
  const int idx = blockIdx.x * 256 + threadIdx.x;   // 0 .. 3*32768-1
  const int l = idx >> 15;
  const int r = idx & 32767;
  const int lane = r & 63, l16 = lane & 15, g4 = lane >> 4;
  const int f  = (r >> 6) & 1, kk = (r >> 7) & 15, mh = (r >> 11) & 1, h = (r >> 12) & 7;
  const int row8 = mh * 32 + f * 16 + l16;
  const float* src = s + ((size_t)l * 512 + 8 * row8 + h) * 512 + kk * 32 + 8 * g4;
  const float4 va = *(const float4*)(src);
  const float4 vb = *(const float4*)(src + 4);
  bf16x8 o = { f2b(va.x), f2b(va.y), f2b(va.z), f2b(va.w),
               f2b(vb.x), f2b(vb.y), f2b(vb.z), f2b(vb.w) };
  *(bf16x8*)(dst + (size_t)blockIdx.y * 786432 + (size_t)l * 262144 + (size_t)r * 8) = o;
}

// Pack biases [3][512] f32 -> [name][l][h][64] f32
__global__ void pack_b(const float* __restrict__ b0, const float* __restrict__ b1,
                       const float* __restrict__ b2, const float* __restrict__ b3,
                       const float* __restrict__ b4, const float* __restrict__ b5,
                       float* __restrict__ dst)
{
  const int idx = blockIdx.x * 256 + threadIdx.x;   // 0..9215
  const int name = idx / 1536;
  const int rem  = idx - name * 1536;
  const int l = rem >> 9;
  const int p = rem & 511;
  const int h = p >> 6, d = p & 63;
  const float* s;
  switch (name) {
    case 0: s = b0; break; case 1: s = b1; break; case 2: s = b2; break;
    case 3: s = b3; break; case 4: s = b4; break; default: s = b5; break;
  }
  dst[idx] = s[l * 512 + 8 * d + h];
}

__global__ void copy_masks(const float* __restrict__ m, float* __restrict__ o) {
  const int i = blockIdx.x * 256 + threadIdx.x;
  ((float4*)o)[i] = ((const float4*)m)[i];
}

extern "C" void kernel_launch(void* const* d_in, const int* in_sizes, int n_in,
                              void* d_out, int out_size, void* d_ws, size_t ws_size,
                              hipStream_t stream)
{
  const float* x0    = (const float*)d_in[0];
  const float* masks = (const float*)d_in[1];
  short* wbf  = (short*)d_ws;                        // packed weights, 9.44 MB
  float* bws  = (float*)((char*)d_ws + 9437184);     // packed biases, 36.9 KB
  float* xbuf = (float*)d_out;                       // x lives in d_out (in-place safe)
  float* mout = xbuf + 16777216;

  pack_w<<<dim3(384, 6), 256, 0, stream>>>(
      (const float*)d_in[2], (const float*)d_in[3], (const float*)d_in[4],
      (const float*)d_in[5], (const float*)d_in[6], (const float*)d_in[7], wbf);
  pack_b<<<36, 256, 0, stream>>>(
      (const float*)d_in[8], (const float*)d_in[9], (const float*)d_in[10],
      (const float*)d_in[11], (const float*)d_in[12], (const float*)d_in[13], bws);
  copy_masks<<<32, 256, 0, stream>>>(masks, mout);

  const size_t WPL = 262144;   // per-(name,layer) packed weight block
  for (int l = 0; l < 3; ++l) {
    attn_pass<0><<<512, 1024, SM_TOTAL, stream>>>(
        (l == 0 ? x0 : xbuf), xbuf,
        wbf + (0 * 3 + l) * WPL, wbf + (1 * 3 + l) * WPL, wbf + (2 * 3 + l) * WPL,
        bws + (0 * 3 + l) * 512, bws + (1 * 3 + l) * 512, bws + (2 * 3 + l) * 512,
        masks);
    attn_pass<1><<<512, 1024, SM_TOTAL, stream>>>(
        xbuf, xbuf,
        wbf + (3 * 3 + l) * WPL, wbf + (4 * 3 + l) * WPL, wbf + (5 * 3 + l) * WPL,
        bws + (3 * 3 + l) * 512, bws + (4 * 3 + l) * 512, bws + (5 * 3 + l) * 512,
        masks);
  }
}

// Round 3
// 1041.479 us; speedup vs baseline: 1.8551x; 1.1001x over previous
//
#include <hip/hip_runtime.h>

#define XS    520   // sh_x row stride (bf16): 512 + 8 pad, rows 1040B
#define KS    72    // k/q/v/w buffer row stride (bf16), rows 144B

#define SM_X     (64 * XS * 2)          // 66560
#define SLOT     (64 * KS * 2)          // 9216 per buffer
#define SM_HD    (2 * SLOT)             // slotA (k->V) + slotB (q->w) per live head
#define SM_MROW  (SM_X + 4 * SM_HD)     // 140288
#define SM_TOTAL (SM_MROW + 256)        // 140544 < 160 KiB

typedef __attribute__((ext_vector_type(4))) float f32x4;
typedef __attribute__((ext_vector_type(8))) short bf16x8;
typedef __attribute__((ext_vector_type(4))) short s16x4;

__device__ __forceinline__ short f2b(float f) {
  union { float f; unsigned u; } v; v.f = f;
  return (short)((v.u + 0x7fffu + ((v.u >> 16) & 1u)) >> 16);   // RNE
}
__device__ __forceinline__ f32x4 mfma16(bf16x8 a, bf16x8 b, f32x4 c) {
  return __builtin_amdgcn_mfma_f32_16x16x32_bf16(a, b, c, 0, 0, 0);
}

// PASS=0: column attention, WG=(b, r): x_local[ch][n] = x[b,ch,r,n]
// PASS=1: row attention,    WG=(b, c): x_local[ch][n] = x[b,ch,n,c]
template <int PASS>
__global__ __launch_bounds__(1024, 4)
void attn_pass(const float* __restrict__ xin, float* __restrict__ xout,
               const short* __restrict__ Wk, const short* __restrict__ Wq,
               const short* __restrict__ Wv,
               const float* __restrict__ bk, const float* __restrict__ bq,
               const float* __restrict__ bv,
               const float* __restrict__ masks)
{
  extern __shared__ char smem[];
  short* sh_x = (short*)smem;
  float* mrow = (float*)(smem + SM_MROW);

  int bid = blockIdx.x;
  if (PASS == 1) bid = (bid & 7) * 64 + (bid >> 3);   // XCD-chunked for L2 locality
  const int b  = bid >> 6;
  const int rc = bid & 63;
  const size_t base = (size_t)b * (512 * 64 * 64);

  const int t    = threadIdx.x;
  const int wv   = t >> 6;
  const int lane = t & 63;
  const int l16  = lane & 15;
  const int g4   = lane >> 4;

  // Wave task maps
  const int p1_j    = wv & 3;           // local head in P1
  const int p1_proj = (wv >> 2) & 1;    // 0 = K, 1 = Q
  const int p1_mh   = wv >> 3;          // which 32-row half
  const int p2_j    = wv >> 2;          // local head in P2 (S+softmax)
  const int p2_qb   = (wv & 3) * 16;    // q-row block
  const int p34_j   = wv & 3;           // local head in P3/P4
  const int p34_qr  = wv >> 2;          // 16-row quarter

  const short* wb_nh = (p1_proj ? Wq : Wk) + p1_mh * 16384 + lane * 8;
  const float* bp1   = (p1_proj ? bq : bk);

  // Prefetch first K/Q fragments for iter 0 (drained by the staging barrier)
  bf16x8 pa0 = *(const bf16x8*)(wb_nh + (size_t)p1_j * 32768);
  bf16x8 pa1 = *(const bf16x8*)(wb_nh + (size_t)p1_j * 32768 + 512);

  // ---- Stage x into LDS as bf16, transposed to [n][ch] ----
  if (PASS == 0) {
    const int n4 = (t & 15) * 4;
    int ch = t >> 4;                    // 0..63
#pragma unroll
    for (int it = 0; it < 8; ++it, ch += 64) {
      float4 v = *(const float4*)(xin + base + (size_t)ch * 4096 + rc * 64 + n4);
      sh_x[(n4 + 0) * XS + ch] = f2b(v.x);
      sh_x[(n4 + 1) * XS + ch] = f2b(v.y);
      sh_x[(n4 + 2) * XS + ch] = f2b(v.z);
      sh_x[(n4 + 3) * XS + ch] = f2b(v.w);
    }
  } else {
    const int n = t & 63;
    const int ch0 = (t >> 6) * 32;
    const float* src = xin + base + n * 64 + rc;
#pragma unroll 8
    for (int k = 0; k < 32; ++k) {
      const int ch = ch0 + k;
      sh_x[n * XS + ch] = f2b(src[(size_t)ch * 4096]);
    }
  }
  if (t < 64) {
    const float m = (PASS == 0) ? masks[b * 4096 + rc * 64 + t]
                                : masks[b * 4096 + t * 64 + rc];
    mrow[t] = (1.0f - m) * 1e8f;
  }
  __syncthreads();

#pragma unroll 1
  for (int g2 = 0; g2 < 2; ++g2) {
    // ---- P1: K & Q projections, one (head, proj, half) per wave, pipelined ----
    {
      const int h = g2 * 4 + p1_j;
      const short* wb = wb_nh + (size_t)h * 32768;
      short* ob = (short*)(smem + SM_X + p1_j * SM_HD) + (p1_proj ? SLOT / 2 : 0);
      f32x4 acc[2][4] = {};
      bf16x8 a0 = pa0, a1 = pa1;
#pragma unroll
      for (int kk = 0; kk < 16; ++kk) {
        bf16x8 n0 = a0, n1 = a1;
        if (kk < 15) {
          n0 = *(const bf16x8*)(wb + (kk + 1) * 1024);
          n1 = *(const bf16x8*)(wb + (kk + 1) * 1024 + 512);
        }
        const int ko = kk * 32 + 8 * g4;
#pragma unroll
        for (int nf = 0; nf < 4; ++nf) {
          bf16x8 bb = *(const bf16x8*)(sh_x + (nf * 16 + l16) * XS + ko);
          acc[0][nf] = mfma16(a0, bb, acc[0][nf]);
          acc[1][nf] = mfma16(a1, bb, acc[1][nf]);
        }
        a0 = n0; a1 = n1;
      }
      const float* bp = bp1 + h * 64;
#pragma unroll
      for (int mi = 0; mi < 2; ++mi) {
        const int db = p1_mh * 32 + mi * 16 + 4 * g4;
        const float4 bs = *(const float4*)(bp + db);
        const float ba[4] = { bs.x, bs.y, bs.z, bs.w };
#pragma unroll
        for (int nf = 0; nf < 4; ++nf) {
          s16x4 pk;
#pragma unroll
          for (int r = 0; r < 4; ++r) pk[r] = f2b(acc[mi][nf][r] + ba[r]);
          *(s16x4*)(ob + (nf * 16 + l16) * KS + db) = pk;   // transposed [n][d]
        }
      }
    }
    __syncthreads();

    // Prefetch first V fragment (drained by the next barrier, hidden under P2)
    const short* wbv = Wv + (size_t)(g2 * 4 + p34_j) * 32768
                     + (p34_qr >> 1) * 16384 + (p34_qr & 1) * 512 + lane * 8;
    bf16x8 pv0 = *(const bf16x8*)(wbv);

    // ---- P2: S = Q.K^T + softmax; w (bf16) overlays qbuf rows (disjoint per wave) ----
    {
      short* sA = (short*)(smem + SM_X + p2_j * SM_HD);            // khT
      short* sB = sA + SLOT / 2;                                    // qhT -> w
      f32x4 st[4] = {};
      const short* qa = sB + (p2_qb + l16) * KS;
#pragma unroll
      for (int dk = 0; dk < 2; ++dk) {
        const int ko = dk * 32 + 8 * g4;
        bf16x8 a = *(const bf16x8*)(qa + ko);
#pragma unroll
        for (int tt = 0; tt < 4; ++tt) {
          bf16x8 bb = *(const bf16x8*)(sA + (tt * 16 + l16) * KS + ko);
          st[tt] = mfma16(a, bb, st[tt]);   // st[tt][r] = S[qb+4g4+r][16tt+l16]
        }
      }
      const float scale = 0.044194173824159216f;   // 1/sqrt(512)
      float v[4][4], mx[4], sm[4];
#pragma unroll
      for (int tt = 0; tt < 4; ++tt) {
        const float pen = mrow[tt * 16 + l16];
#pragma unroll
        for (int r = 0; r < 4; ++r) v[tt][r] = st[tt][r] * scale - pen;
      }
#pragma unroll
      for (int r = 0; r < 4; ++r)
        mx[r] = fmaxf(fmaxf(v[0][r], v[1][r]), fmaxf(v[2][r], v[3][r]));
#pragma unroll
      for (int d = 1; d <= 8; d <<= 1)
#pragma unroll
        for (int r = 0; r < 4; ++r) mx[r] = fmaxf(mx[r], __shfl_xor(mx[r], d));
#pragma unroll
      for (int r = 0; r < 4; ++r) sm[r] = 0.f;
#pragma unroll
      for (int tt = 0; tt < 4; ++tt)
#pragma unroll
        for (int r = 0; r < 4; ++r) { v[tt][r] = __expf(v[tt][r] - mx[r]); sm[r] += v[tt][r]; }
#pragma unroll
      for (int d = 1; d <= 8; d <<= 1)
#pragma unroll
        for (int r = 0; r < 4; ++r) sm[r] += __shfl_xor(sm[r], d);
#pragma unroll
      for (int r = 0; r < 4; ++r) sm[r] = 1.0f / sm[r];
#pragma unroll
      for (int tt = 0; tt < 4; ++tt)
#pragma unroll
        for (int r = 0; r < 4; ++r)
          sB[(p2_qb + 4 * g4 + r) * KS + tt * 16 + l16] = f2b(v[tt][r] * sm[r]);
    }
    __syncthreads();

    // ---- P3: V projection quarter-head per wave, pipelined; V overlays kbuf ----
    {
      short* sA = (short*)(smem + SM_X + p34_j * SM_HD);   // V destination
      f32x4 acc[4] = {};
      bf16x8 a = pv0;
#pragma unroll
      for (int kk = 0; kk < 16; ++kk) {
        bf16x8 na = a;
        if (kk < 15) na = *(const bf16x8*)(wbv + (kk + 1) * 1024);
        const int ko = kk * 32 + 8 * g4;
#pragma unroll
        for (int nf = 0; nf < 4; ++nf) {
          bf16x8 bb = *(const bf16x8*)(sh_x + (nf * 16 + l16) * XS + ko);
          acc[nf] = mfma16(a, bb, acc[nf]);
        }
        a = na;
      }
      const int db = p34_qr * 16 + 4 * g4;
      const float4 bs = *(const float4*)(bv + (g2 * 4 + p34_j) * 64 + db);
      const float ba[4] = { bs.x, bs.y, bs.z, bs.w };
#pragma unroll
      for (int nf = 0; nf < 4; ++nf)
#pragma unroll
        for (int r = 0; r < 4; ++r)
          sA[(db + r) * KS + nf * 16 + l16] = f2b(acc[nf][r] + ba[r]);   // V[d][n]
    }
    __syncthreads();

    // ---- P4: O = V.w^T (quarter-head per wave) + fp32 residual writeback ----
    {
      const int h = g2 * 4 + p34_j;
      short* sA = (short*)(smem + SM_X + p34_j * SM_HD);   // V
      short* sB = sA + SLOT / 2;                            // w
      f32x4 oc[4] = {};
      const short* va = sA + (p34_qr * 16 + l16) * KS;
#pragma unroll
      for (int dk = 0; dk < 2; ++dk) {
        const int ko = dk * 32 + 8 * g4;
        bf16x8 a = *(const bf16x8*)(va + ko);
#pragma unroll
        for (int nf = 0; nf < 4; ++nf) {
          bf16x8 bb = *(const bf16x8*)(sB + (nf * 16 + l16) * KS + ko);
          oc[nf] = mfma16(a, bb, oc[nf]);
        }
      }
#pragma unroll
      for (int nf = 0; nf < 4; ++nf) {
        const int q = nf * 16 + l16;
#pragma unroll
        for (int r = 0; r < 4; ++r) {
          const int d  = p34_qr * 16 + 4 * g4 + r;
          const int ch = 8 * d + h;
          const size_t off = (PASS == 0)
              ? base + (size_t)ch * 4096 + rc * 64 + q
              : base + (size_t)ch * 4096 + q * 64 + rc;
          xout[off] = oc[nf][r] + xin[off];
        }
      }
      // Prefetch iter-1 K/Q first fragments (drained by the barrier below)
      if (g2 == 0) {
        const short* wb2 = wb_nh + (size_t)(4 + p1_j) * 32768;
        pa0 = *(const bf16x8*)(wb2);
        pa1 = *(const bf16x8*)(wb2 + 512);
      }
    }
    __syncthreads();
  }
}

// Pack 6 weight tensors [3][512][512] f32 -> MFMA-fragment-ordered bf16:
// dst[(name*3+l)*262144 + ((((h*2+mh)*16+kk)*2+f)*64+lane)*8 + j]
//   = W[l][8*(mh*32+f*16+(lane&15))+h][kk*32+8*(lane>>4)+j]
__global__ void pack_w(const float* __restrict__ w0, const float* __restrict__ w1,
                       const float* __restrict__ w2, const float* __restrict__ w3,
                       const float* __restrict__ w4, const float* __restrict__ w5,
                       short* __restrict__ dst)
{
  const float* s;
  switch (blockIdx.y) {
    case 0: s = w0; break; case 1: s = w1; break; case 2: s = w2; break;
    case 3: s = w3; break; case 4: s = w4; break; default: s = w5; break;
  }
  const int idx = blockIdx.x * 256 + threadIdx.x;   // 0 .. 3*32768-1
  const int l = idx >> 15;
  const int r = idx & 32767;
  const int lane = r & 63, l16 = lane & 15, g4 = lane >> 4;
  const int f  = (r >> 6) & 1, kk = (r >> 7) & 15, mh = (r >> 11) & 1, h = (r >> 12) & 7;
  const int row8 = mh * 32 + f * 16 + l16;
  const float* src = s + ((size_t)l * 512 + 8 * row8 + h) * 512 + kk * 32 + 8 * g4;
  const float4 va = *(const float4*)(src);
  const float4 vb = *(const float4*)(src + 4);
  bf16x8 o = { f2b(va.x), f2b(va.y), f2b(va.z), f2b(va.w),
               f2b(vb.x), f2b(vb.y), f2b(vb.z), f2b(vb.w) };
  *(bf16x8*)(dst + (size_t)blockIdx.y * 786432 + (size_t)l * 262144 + (size_t)r * 8) = o;
}

// Pack biases [3][512] f32 -> [name][l][h][64] f32
__global__ void pack_b(const float* __restrict__ b0, const float* __restrict__ b1,
                       const float* __restrict__ b2, const float* __restrict__ b3,
                       const float* __restrict__ b4, const float* __restrict__ b5,
                       float* __restrict__ dst)
{
  const int idx = blockIdx.x * 256 + threadIdx.x;   // 0..9215
  const int name = idx / 1536;
  const int rem  = idx - name * 1536;
  const int l = rem >> 9;
  const int p = rem & 511;
  const int h = p >> 6, d = p & 63;
  const float* s;
  switch (name) {
    case 0: s = b0; break; case 1: s = b1; break; case 2: s = b2; break;
    case 3: s = b3; break; case 4: s = b4; break; default: s = b5; break;
  }
  dst[idx] = s[l * 512 + 8 * d + h];
}

__global__ void copy_masks(const float* __restrict__ m, float* __restrict__ o) {
  const int i = blockIdx.x * 256 + threadIdx.x;
  ((float4*)o)[i] = ((const float4*)m)[i];
}

extern "C" void kernel_launch(void* const* d_in, const int* in_sizes, int n_in,
                              void* d_out, int out_size, void* d_ws, size_t ws_size,
                              hipStream_t stream)
{
  const float* x0    = (const float*)d_in[0];
  const float* masks = (const float*)d_in[1];
  short* wbf  = (short*)d_ws;                        // packed weights, 9.44 MB
  float* bws  = (float*)((char*)d_ws + 9437184);     // packed biases
  float* xbuf = (float*)d_out;                       // x lives in d_out (in-place safe)
  float* mout = xbuf + 16777216;

  pack_w<<<dim3(384, 6), 256, 0, stream>>>(
      (const float*)d_in[2], (const float*)d_in[3], (const float*)d_in[4],
      (const float*)d_in[5], (const float*)d_in[6], (const float*)d_in[7], wbf);
  pack_b<<<36, 256, 0, stream>>>(
      (const float*)d_in[8], (const float*)d_in[9], (const float*)d_in[10],
      (const float*)d_in[11], (const float*)d_in[12], (const float*)d_in[13], bws);
  copy_masks<<<32, 256, 0, stream>>>(masks, mout);

  const size_t WPL = 262144;   // per-(name,layer) packed weight block
  for (int l = 0; l < 3; ++l) {
    attn_pass<0><<<512, 1024, SM_TOTAL, stream>>>(
        (l == 0 ? x0 : xbuf), xbuf,
        wbf + (0 * 3 + l) * WPL, wbf + (1 * 3 + l) * WPL, wbf + (2 * 3 + l) * WPL,
        bws + (0 * 3 + l) * 512, bws + (1 * 3 + l) * 512, bws + (2 * 3 + l) * 512,
        masks);
    attn_pass<1><<<512, 1024, SM_TOTAL, stream>>>(
        xbuf, xbuf,
        wbf + (3 * 3 + l) * WPL, wbf + (4 * 3 + l) * WPL, wbf + (5 * 3 + l) * WPL,
        bws + (3 * 3 + l) * 512, bws + (4 * 3 + l) * 512, bws + (5 * 3 + l) * 512,
        masks);
  }
}

// Round 5
// 826.387 us; speedup vs baseline: 2.3379x; 1.2603x over previous
//
#include <hip/hip_runtime.h>

// LDS geometry: sh_x rows stride 1152B (64 rows), head slots 64 rows x 128B.
#define SM_X     73728                  // 64 * 1152
#define SM_HD    16384                  // kslot(8KB: khT -> V) + qslot(8KB: qhT -> w)
#define SM_MROW  (SM_X + 4 * SM_HD)     // 139264
#define SM_TOTAL (SM_MROW + 256)        // 139520 < 160 KiB

typedef __attribute__((ext_vector_type(4))) float f32x4;
typedef __attribute__((ext_vector_type(8))) short bf16x8;
typedef __attribute__((ext_vector_type(4))) short s16x4;

__device__ __forceinline__ short f2b(float f) {
  union { float f; unsigned u; } v; v.f = f;
  return (short)((v.u + 0x7fffu + ((v.u >> 16) & 1u)) >> 16);   // RNE
}
__device__ __forceinline__ f32x4 mfma16(bf16x8 a, bf16x8 b, f32x4 c) {
  return __builtin_amdgcn_mfma_f32_16x16x32_bf16(a, b, c, 0, 0, 0);
}

// XOR-swizzled LDS addressing. Row strides (1152 / 128) have zero low-7 bits,
// so the bit4-6 XOR folds into the in-row offset exactly.
__device__ __forceinline__ void* xsw(void* base, int row, int boff) {
  return (char*)base + row * 1152 + (boff ^ ((row & 7) << 4));
}
__device__ __forceinline__ void* ksw(void* base, int row, int boff) {
  return (char*)base + (row << 7) + (boff ^ ((row & 7) << 4));
}

// x lives in xw[b][nr][nc][p], p = h*64 + d  (original channel ch = 8d + h).
// PASS=0 (col attn): WG (b, r=rc): x_local[n=nc][p] = xw[b][rc][n][p]
// PASS=1 (row attn): WG (b, c=rc): x_local[n=nr][p] = xw[b][n][rc][p]
// FINAL: epilogue writes standard layout out[b][ch][nr][nc] instead of xw.
template <int PASS, int FINAL>
__global__ __launch_bounds__(1024, 4)
void attn_pass(float* __restrict__ xw, float* __restrict__ outp,
               const short* __restrict__ Wk, const short* __restrict__ Wq,
               const short* __restrict__ Wv,
               const float* __restrict__ bk, const float* __restrict__ bq,
               const float* __restrict__ bv,
               const float* __restrict__ masks)
{
  extern __shared__ char smem[];
  short* sh_x = (short*)smem;
  float* mrow = (float*)(smem + SM_MROW);

  int bid = blockIdx.x;
  if (PASS == 1) bid = (bid & 7) * 64 + (bid >> 3);   // XCD-chunked
  const int b  = bid >> 6;
  const int rc = bid & 63;

  const int t    = threadIdx.x;
  const int wv   = t >> 6;
  const int lane = t & 63;
  const int l16  = lane & 15;
  const int g4   = lane >> 4;

  const int p1_j = wv & 3, p1_proj = (wv >> 2) & 1, p1_mh = wv >> 3;
  const int p2_j = wv >> 2, p2_qb = (wv & 3) * 16;
  const int p34_j = wv & 3, p34_qr = wv >> 2;

  const short* wb_nh = (p1_proj ? Wq : Wk) + p1_mh * 16384 + lane * 8;
  const float* bp1   = p1_proj ? bq : bk;
  bf16x8 pa0 = *(const bf16x8*)(wb_nh + p1_j * 32768);
  bf16x8 pa1 = *(const bf16x8*)(wb_nh + p1_j * 32768 + 512);

  // ---- Stage: coalesced 16B/lane reads, 8B swizzled LDS writes ----
#pragma unroll
  for (int it = 0; it < 8; ++it) {
    const int idx = it * 1024 + t;
    const int n = idx >> 7, inner = idx & 127;
    const size_t gofs = (PASS == 0)
        ? (size_t)((b * 64 + rc) * 64 + n) * 512 + inner * 4
        : (size_t)((b * 64 + n) * 64 + rc) * 512 + inner * 4;
    const float4 v = *(const float4*)(xw + gofs);
    s16x4 pk = { f2b(v.x), f2b(v.y), f2b(v.z), f2b(v.w) };
    *(s16x4*)xsw(sh_x, n, inner * 8) = pk;
  }
  if (t < 64) {
    const float m = (PASS == 0) ? masks[b * 4096 + rc * 64 + t]
                                : masks[b * 4096 + t * 64 + rc];
    mrow[t] = (1.0f - m) * 1e8f;
  }
  __syncthreads();

#pragma unroll 1
  for (int g2 = 0; g2 < 2; ++g2) {
    // ---- P1: K (waves proj=0) / Q (proj=1) projections, pipelined ----
    {
      const int h = g2 * 4 + p1_j;
      const short* wb = wb_nh + h * 32768;
      char* gb = smem + SM_X + p1_j * SM_HD;
      short* ob = (short*)(gb + (p1_proj ? 8192 : 0));
      f32x4 acc[2][4] = {};
      bf16x8 a0 = pa0, a1 = pa1;
#pragma unroll
      for (int kk = 0; kk < 16; ++kk) {
        bf16x8 n0 = a0, n1 = a1;
        if (kk < 15) {
          n0 = *(const bf16x8*)(wb + (kk + 1) * 1024);
          n1 = *(const bf16x8*)(wb + (kk + 1) * 1024 + 512);
        }
        const int bo = kk * 64 + 16 * g4;
#pragma unroll
        for (int nf = 0; nf < 4; ++nf) {
          bf16x8 bb = *(const bf16x8*)xsw(sh_x, nf * 16 + l16, bo);
          acc[0][nf] = mfma16(a0, bb, acc[0][nf]);
          acc[1][nf] = mfma16(a1, bb, acc[1][nf]);
        }
        a0 = n0; a1 = n1;
      }
      const float* bp = bp1 + h * 64;
#pragma unroll
      for (int mi = 0; mi < 2; ++mi) {
        const int db = p1_mh * 32 + mi * 16 + 4 * g4;
        const float4 bs = *(const float4*)(bp + db);
        const float ba[4] = { bs.x, bs.y, bs.z, bs.w };
#pragma unroll
        for (int nf = 0; nf < 4; ++nf) {
          s16x4 pk;
#pragma unroll
          for (int r = 0; r < 4; ++r) pk[r] = f2b(acc[mi][nf][r] + ba[r]);
          *(s16x4*)ksw(ob, nf * 16 + l16, 2 * db) = pk;   // khT/qhT [n][d]
        }
      }
    }
    __syncthreads();

    // Prefetch first V fragment (hidden under P2)
    const short* wbv = Wv + (size_t)(g2 * 4 + p34_j) * 32768
                     + (p34_qr >> 1) * 16384 + (p34_qr & 1) * 512 + lane * 8;
    bf16x8 pv0 = *(const bf16x8*)(wbv);

    // ---- P2: S^T = Q.K^T + softmax over keys; w overlays qslot rows ----
    {
      char* gb = smem + SM_X + p2_j * SM_HD;
      short* kb  = (short*)gb;
      short* qb_ = (short*)(gb + 8192);
      f32x4 st[4] = {};
#pragma unroll
      for (int dk = 0; dk < 2; ++dk) {
        const int bo = dk * 64 + 16 * g4;
        bf16x8 a = *(const bf16x8*)ksw(qb_, p2_qb + l16, bo);
#pragma unroll
        for (int tt = 0; tt < 4; ++tt) {
          bf16x8 bb = *(const bf16x8*)ksw(kb, tt * 16 + l16, bo);
          st[tt] = mfma16(a, bb, st[tt]);   // st[tt][r]=S[q=qb+4g4+r][key=16tt+l16]
        }
      }
      const float scale = 0.044194173824159216f;   // 1/sqrt(512)
      float v[4][4], mx[4], sm[4];
#pragma unroll
      for (int tt = 0; tt < 4; ++tt) {
        const float pen = mrow[tt * 16 + l16];
#pragma unroll
        for (int r = 0; r < 4; ++r) v[tt][r] = st[tt][r] * scale - pen;
      }
#pragma unroll
      for (int r = 0; r < 4; ++r)
        mx[r] = fmaxf(fmaxf(v[0][r], v[1][r]), fmaxf(v[2][r], v[3][r]));
#pragma unroll
      for (int d = 1; d <= 8; d <<= 1)
#pragma unroll
        for (int r = 0; r < 4; ++r) mx[r] = fmaxf(mx[r], __shfl_xor(mx[r], d));
#pragma unroll
      for (int r = 0; r < 4; ++r) sm[r] = 0.f;
#pragma unroll
      for (int tt = 0; tt < 4; ++tt)
#pragma unroll
        for (int r = 0; r < 4; ++r) { v[tt][r] = __expf(v[tt][r] - mx[r]); sm[r] += v[tt][r]; }
#pragma unroll
      for (int d = 1; d <= 8; d <<= 1)
#pragma unroll
        for (int r = 0; r < 4; ++r) sm[r] += __shfl_xor(sm[r], d);
#pragma unroll
      for (int r = 0; r < 4; ++r) sm[r] = 1.0f / sm[r];
#pragma unroll
      for (int tt = 0; tt < 4; ++tt)
#pragma unroll
        for (int r = 0; r < 4; ++r)
          *(short*)ksw(qb_, p2_qb + 4 * g4 + r, 2 * (tt * 16 + l16)) =
              f2b(v[tt][r] * sm[r]);   // w[q][key]
    }
    __syncthreads();

    // ---- P3: V projection (quarter-head per wave), V[d][key] overlays kslot ----
    {
      char* gb = smem + SM_X + p34_j * SM_HD;
      short* vbuf = (short*)gb;
      f32x4 acc[4] = {};
      bf16x8 a = pv0;
#pragma unroll
      for (int kk = 0; kk < 16; ++kk) {
        bf16x8 na = a;
        if (kk < 15) na = *(const bf16x8*)(wbv + (kk + 1) * 1024);
        const int bo = kk * 64 + 16 * g4;
#pragma unroll
        for (int nf = 0; nf < 4; ++nf) {
          bf16x8 bb = *(const bf16x8*)xsw(sh_x, nf * 16 + l16, bo);
          acc[nf] = mfma16(a, bb, acc[nf]);
        }
        a = na;
      }
      const int db = p34_qr * 16 + 4 * g4;
      const float4 bs = *(const float4*)(bv + (g2 * 4 + p34_j) * 64 + db);
      const float ba[4] = { bs.x, bs.y, bs.z, bs.w };
#pragma unroll
      for (int nf = 0; nf < 4; ++nf)
#pragma unroll
        for (int r = 0; r < 4; ++r)
          *(short*)ksw(vbuf, db + r, 2 * (nf * 16 + l16)) = f2b(acc[nf][r] + ba[r]);
    }
    __syncthreads();

    // ---- P4: O^T[q][d] = sum_key w[q][key] V[d][key]; lane-contiguous epilogue ----
    {
      const int h = g2 * 4 + p34_j;
      char* gb = smem + SM_X + p34_j * SM_HD;
      short* vbuf = (short*)gb;
      short* wbuf = (short*)(gb + 8192);
      f32x4 oc[4] = {};
#pragma unroll
      for (int dk = 0; dk < 2; ++dk) {
        const int bo = dk * 64 + 16 * g4;
        bf16x8 a = *(const bf16x8*)ksw(wbuf, p34_qr * 16 + l16, bo);
#pragma unroll
        for (int nf = 0; nf < 4; ++nf) {
          bf16x8 bb = *(const bf16x8*)ksw(vbuf, nf * 16 + l16, bo);
          oc[nf] = mfma16(a, bb, oc[nf]);
        }
      }
#pragma unroll
      for (int nf = 0; nf < 4; ++nf) {
        const int dcol = nf * 16 + l16;
        const int p = h * 64 + dcol;
#pragma unroll
        for (int r = 0; r < 4; ++r) {
          const int q = p34_qr * 16 + 4 * g4 + r;
          const size_t rofs = (PASS == 0)
              ? (size_t)((b * 64 + rc) * 64 + q) * 512 + p
              : (size_t)((b * 64 + q) * 64 + rc) * 512 + p;
          const float val = oc[nf][r] + xw[rofs];
          if (FINAL)
            outp[(size_t)b * 2097152 + (size_t)(8 * dcol + h) * 4096 + q * 64 + rc] = val;
          else
            xw[rofs] = val;
        }
      }
      if (g2 == 0) {   // prefetch iter-1 K/Q fragments (drained by barrier)
        const short* wb2 = wb_nh + (4 + p1_j) * 32768;
        pa0 = *(const bf16x8*)(wb2);
        pa1 = *(const bf16x8*)(wb2 + 512);
      }
    }
    __syncthreads();
  }
}

// x[b][ch][nr][nc] f32 -> xw[b][nr][nc][p], p = h*64+d, ch = 8d+h. LDS-tiled.
// Tile row stride 521 floats: padded index pp = p + (p>>6) has max 518 < 521
// (517 overlapped adjacent rows -- the R4 corruption bug); 4*521 % 32 == 4
// keeps the transpose writes ~2-way bank-aliased.
__global__ __launch_bounds__(256)
void prep_x(const float* __restrict__ x, float* __restrict__ xw)
{
  extern __shared__ float tile[];            // [nc=64][521]
  const int b = blockIdx.x >> 6, nr = blockIdx.x & 63;
  const float* src = x + (size_t)b * 2097152 + nr * 64;
  const int t = threadIdx.x;
#pragma unroll 4
  for (int it = 0; it < 32; ++it) {
    const int idx = it * 256 + t;
    const int ch = idx >> 4, nc4 = (idx & 15) * 4;
    const float4 v = *(const float4*)(src + (size_t)ch * 4096 + nc4);
    const int p = ((ch & 7) << 6) | (ch >> 3);
    const int pp = p + (p >> 6);
    tile[(nc4 + 0) * 521 + pp] = v.x;
    tile[(nc4 + 1) * 521 + pp] = v.y;
    tile[(nc4 + 2) * 521 + pp] = v.z;
    tile[(nc4 + 3) * 521 + pp] = v.w;
  }
  __syncthreads();
  float* dst = xw + (size_t)(b * 64 + nr) * 32768;
#pragma unroll 4
  for (int it = 0; it < 32; ++it) {
    const int idx = it * 256 + t;
    const int nc = idx >> 7, p4 = (idx & 127) * 4;
    float4 o;
#pragma unroll
    for (int j = 0; j < 4; ++j) {
      const int p = p4 + j;
      (&o.x)[j] = tile[nc * 521 + p + (p >> 6)];
    }
    *(float4*)(dst + (size_t)nc * 512 + p4) = o;
  }
}

// Fallback un-permute of one b-block: tmp[nr][nc][p] -> out[ch][nr][nc]
__global__ __launch_bounds__(256)
void unperm_b(const float* __restrict__ tmp, float* __restrict__ out)
{
  __shared__ float tile[64 * 65];
  const int nr = blockIdx.x >> 3, pb = blockIdx.x & 7;
#pragma unroll
  for (int it = 0; it < 4; ++it) {
    const int idx = it * 256 + threadIdx.x;
    const int nc = idx >> 4, p4 = (idx & 15) * 4;
    const float4 v = *(const float4*)(tmp + (size_t)(nr * 64 + nc) * 512 + pb * 64 + p4);
    tile[nc * 65 + p4 + 0] = v.x; tile[nc * 65 + p4 + 1] = v.y;
    tile[nc * 65 + p4 + 2] = v.z; tile[nc * 65 + p4 + 3] = v.w;
  }
  __syncthreads();
#pragma unroll
  for (int it = 0; it < 4; ++it) {
    const int idx = it * 256 + threadIdx.x;
    const int pi = idx >> 4, nc4 = (idx & 15) * 4;
    const int ch = 8 * pi + pb;
    float4 o;
#pragma unroll
    for (int j = 0; j < 4; ++j) (&o.x)[j] = tile[(nc4 + j) * 65 + pi];
    *(float4*)(out + (size_t)ch * 4096 + nr * 64 + nc4) = o;
  }
}

// Weights [3][512][512] f32 -> fragment order with k-elements in p-order.
// dst[((((h*2+mh)*16+kk)*2+f)*64+lane)*8 + j] = W[o = 8*(mh*32+f*16+(lane&15))+h]
//                                                [ch(p = kk*32+8*(lane>>4)+j)]
__global__ void pack_w(const float* __restrict__ w0, const float* __restrict__ w1,
                       const float* __restrict__ w2, const float* __restrict__ w3,
                       const float* __restrict__ w4, const float* __restrict__ w5,
                       short* __restrict__ dst)
{
  const float* s;
  switch (blockIdx.y) {
    case 0: s = w0; break; case 1: s = w1; break; case 2: s = w2; break;
    case 3: s = w3; break; case 4: s = w4; break; default: s = w5; break;
  }
  const int idx = blockIdx.x * 256 + threadIdx.x;   // 0 .. 196607
  const int l = idx >> 16;
  const int r = idx & 65535;
  const int o = r >> 7, c4 = (r & 127) * 4;
  const float4 v = *(const float4*)(s + ((size_t)l * 512 + o) * 512 + c4);
  const int h = o & 7, row8 = o >> 3;
  const int mh = row8 >> 5, f = (row8 >> 4) & 1, l16r = row8 & 15;
  short* db = dst + (size_t)blockIdx.y * 786432 + (size_t)l * 262144;
#pragma unroll
  for (int j = 0; j < 4; ++j) {
    const int ch = c4 + j;
    const int p = ((ch & 7) << 6) | (ch >> 3);
    const int jj = p & 7, g4p = (p >> 3) & 3, kk = p >> 5;
    const int lane = g4p * 16 + l16r;
    db[(size_t)(((((h * 2 + mh) * 16 + kk) * 2 + f) * 64 + lane)) * 8 + jj] =
        f2b((&v.x)[j]);
  }
}

// Biases [3][512] f32 -> [name][l][h][64] f32
__global__ void pack_b(const float* __restrict__ b0, const float* __restrict__ b1,
                       const float* __restrict__ b2, const float* __restrict__ b3,
                       const float* __restrict__ b4, const float* __restrict__ b5,
                       float* __restrict__ dst)
{
  const int idx = blockIdx.x * 256 + threadIdx.x;   // 0..9215
  const int name = idx / 1536;
  const int rem  = idx - name * 1536;
  const int l = rem >> 9;
  const int p = rem & 511;
  const int h = p >> 6, d = p & 63;
  const float* s;
  switch (name) {
    case 0: s = b0; break; case 1: s = b1; break; case 2: s = b2; break;
    case 3: s = b3; break; case 4: s = b4; break; default: s = b5; break;
  }
  dst[idx] = s[l * 512 + 8 * d + h];
}

__global__ void copy_masks(const float* __restrict__ m, float* __restrict__ o) {
  const int i = blockIdx.x * 256 + threadIdx.x;
  ((float4*)o)[i] = ((const float4*)m)[i];
}

extern "C" void kernel_launch(void* const* d_in, const int* in_sizes, int n_in,
                              void* d_out, int out_size, void* d_ws, size_t ws_size,
                              hipStream_t stream)
{
  const float* x0    = (const float*)d_in[0];
  const float* masks = (const float*)d_in[1];
  short* wbf  = (short*)d_ws;                        // packed weights, 9.44 MB
  float* bws  = (float*)((char*)d_ws + 9437184);     // packed biases, 36.9 KB
  float* xbuf = (float*)d_out;
  float* mout = xbuf + 16777216;

  const size_t xw_off = 9474048;                     // 9437184 + 36864
  const bool big = ws_size >= xw_off + (size_t)67108864;
  float* xw = big ? (float*)((char*)d_ws + xw_off) : xbuf;

  pack_w<<<dim3(768, 6), 256, 0, stream>>>(
      (const float*)d_in[2], (const float*)d_in[3], (const float*)d_in[4],
      (const float*)d_in[5], (const float*)d_in[6], (const float*)d_in[7], wbf);
  pack_b<<<36, 256, 0, stream>>>(
      (const float*)d_in[8], (const float*)d_in[9], (const float*)d_in[10],
      (const float*)d_in[11], (const float*)d_in[12], (const float*)d_in[13], bws);
  prep_x<<<512, 256, 64 * 521 * 4, stream>>>(x0, xw);
  copy_masks<<<32, 256, 0, stream>>>(masks, mout);

  const size_t WPL = 262144;
  for (int l = 0; l < 3; ++l) {
    attn_pass<0, 0><<<512, 1024, SM_TOTAL, stream>>>(
        xw, xbuf,
        wbf + (0 * 3 + l) * WPL, wbf + (1 * 3 + l) * WPL, wbf + (2 * 3 + l) * WPL,
        bws + (0 * 3 + l) * 512, bws + (1 * 3 + l) * 512, bws + (2 * 3 + l) * 512,
        masks);
    const short* rwk = wbf + (3 * 3 + l) * WPL;
    const short* rwq = wbf + (4 * 3 + l) * WPL;
    const short* rwv = wbf + (5 * 3 + l) * WPL;
    const float* rbk = bws + (3 * 3 + l) * 512;
    const float* rbq = bws + (4 * 3 + l) * 512;
    const float* rbv = bws + (5 * 3 + l) * 512;
    if (l == 2 && big)
      attn_pass<1, 1><<<512, 1024, SM_TOTAL, stream>>>(
          xw, xbuf, rwk, rwq, rwv, rbk, rbq, rbv, masks);
    else
      attn_pass<1, 0><<<512, 1024, SM_TOTAL, stream>>>(
          xw, xbuf, rwk, rwq, rwv, rbk, rbq, rbv, masks);
  }

  if (!big) {
    // xw aliased d_out in p-layout; un-permute per b-block via ws bounce.
    for (int b = 0; b < 8; ++b) {
      hipMemcpyAsync(wbf, xw + (size_t)b * 2097152, 8388608,
                     hipMemcpyDeviceToDevice, stream);
      unperm_b<<<512, 256, 0, stream>>>((const float*)wbf,
                                        xbuf + (size_t)b * 2097152);
    }
  }
}

// Round 6
// 770.467 us; speedup vs baseline: 2.5076x; 1.0726x over previous
//
#include <hip/hip_runtime.h>

// LDS: sh_x 64 rows x 1024B (bf16, swizzle baked into data) + 4 head slots.
#define SM_X     65536
#define SM_HD    16384                  // kslot(8KB: khT -> V) + qslot(8KB: qhT -> w)
#define SM_MROW  (SM_X + 4 * SM_HD)     // 131072
#define SM_TOTAL (SM_MROW + 256)        // 131328 < 160 KiB

typedef __attribute__((ext_vector_type(4))) float f32x4;
typedef __attribute__((ext_vector_type(8))) short bf16x8;
typedef __attribute__((ext_vector_type(4))) short s16x4;

__device__ __forceinline__ short f2b(float f) {
  union { float f; unsigned u; } v; v.f = f;
  return (short)((v.u + 0x7fffu + ((v.u >> 16) & 1u)) >> 16);   // RNE
}
__device__ __forceinline__ float b2f(short u) {
  union { unsigned u; float f; } v; v.u = ((unsigned)(unsigned short)u) << 16;
  return v.f;
}
__device__ __forceinline__ f32x4 mfma16(bf16x8 a, bf16x8 b, f32x4 c) {
  return __builtin_amdgcn_mfma_f32_16x16x32_bf16(a, b, c, 0, 0, 0);
}

// 8KB head-slot swizzle (64 rows x 128B), same as R5.
__device__ __forceinline__ void* ksw(void* base, int row, int boff) {
  return (char*)base + (row << 7) + (boff ^ ((row & 7) << 4));
}

// xw[b][nr][nc][p] bf16, p = h*64+d (ch = 8d+h); within each 1KB row the byte
// offset is stored XOR'ed with ((nr^nc)&7)<<4.  For a WG with fixed rc this is
// the per-lane constant ((l16^rc)&7)<<4 for every row it touches.
// PASS=0 (col attn): WG (b, rc=nr): sh_x row n = nc.  rows contiguous (64KB slab)
// PASS=1 (row attn): WG (b, rc=nc): sh_x row n = nr.  rows strided 64KB
// FINAL: epilogue writes standard fp32 out[b][ch][nr][nc] instead of xw.
template <int PASS, int FINAL>
__global__ __launch_bounds__(1024, 4)
void attn_pass(unsigned short* __restrict__ xw, float* __restrict__ outp,
               const short* __restrict__ Wk, const short* __restrict__ Wq,
               const short* __restrict__ Wv,
               const float* __restrict__ bk, const float* __restrict__ bq,
               const float* __restrict__ bv,
               const float* __restrict__ masks)
{
  extern __shared__ char smem[];
  float* mrow = (float*)(smem + SM_MROW);

  int bid = blockIdx.x;
  if (PASS == 1) bid = (bid & 7) * 64 + (bid >> 3);   // XCD-chunked
  const int b  = bid >> 6;
  const int rc = bid & 63;

  const int t    = threadIdx.x;
  const int wv   = t >> 6;
  const int lane = t & 63;
  const int l16  = lane & 15;
  const int g4   = lane >> 4;

  const int sxl  = ((l16 ^ rc) & 7) << 4;   // sh_x swizzle const for this lane
  const int sx30 = sxl & 0x30;
  const int sx64 = sxl & 0x40;

  const int p1_j = wv & 3, p1_proj = (wv >> 2) & 1, p1_mh = wv >> 3;
  const int p2_j = wv >> 2, p2_qb = (wv & 3) * 16;
  const int p34_j = wv & 3, p34_qr = wv >> 2;

  const short* wb_nh = (p1_proj ? Wq : Wk) + p1_mh * 16384 + lane * 8;
  const float* bp1   = p1_proj ? bq : bk;
  // Depth-2 K/Q prefetch for g2=0 (in flight across the staging barrier)
  bf16x8 pa0 = *(const bf16x8*)(wb_nh + p1_j * 32768);
  bf16x8 pa1 = *(const bf16x8*)(wb_nh + p1_j * 32768 + 512);
  bf16x8 pa2 = *(const bf16x8*)(wb_nh + p1_j * 32768 + 1024);
  bf16x8 pa3 = *(const bf16x8*)(wb_nh + p1_j * 32768 + 1536);

  // ---- Stage: straight 16B copy (data pre-swizzled + pre-converted) ----
  {
    const char* xb = (const char*)xw;
    const char* srcb = (PASS == 0)
        ? xb + (size_t)((b * 64 + rc) * 64) * 1024
        : xb + (size_t)(b * 4096 + rc) * 1024;
#pragma unroll
    for (int it = 0; it < 4; ++it) {
      const int idx = it * 1024 + t;
      const int n = idx >> 6, c = idx & 63;
      const char* g = (PASS == 0) ? srcb + n * 1024 + c * 16
                                  : srcb + (size_t)n * 65536 + c * 16;
      *(bf16x8*)(smem + n * 1024 + c * 16) = *(const bf16x8*)g;
    }
  }
  if (t < 64) {
    const float m = (PASS == 0) ? masks[b * 4096 + rc * 64 + t]
                                : masks[b * 4096 + t * 64 + rc];
    mrow[t] = (1.0f - m) * 1e8f;
  }
  __syncthreads();

  // Per-thread sh_x fragment base (row l16 + g4 k-offset, swizzle folded)
  const char* xfb = smem + l16 * 1024 + ((16 * g4) ^ sx30);

#pragma unroll 1
  for (int g2 = 0; g2 < 2; ++g2) {
    // ---- P1: K/Q projections (one (head, proj, half) per wave), depth-2 ----
    {
      const int h = g2 * 4 + p1_j;
      const short* wb = wb_nh + h * 32768;
      char* gb = smem + SM_X + p1_j * SM_HD;
      short* ob = (short*)(gb + (p1_proj ? 8192 : 0));
      f32x4 acc[2][4] = {};
      bf16x8 c0a = pa0, c0b = pa1, c1a = pa2, c1b = pa3;
#pragma unroll
      for (int kk = 0; kk < 16; ++kk) {
        bf16x8 nna = c1a, nnb = c1b;
        if (kk < 14) {
          nna = *(const bf16x8*)(wb + (kk + 2) * 1024);
          nnb = *(const bf16x8*)(wb + (kk + 2) * 1024 + 512);
        }
        const int off = (kk * 64) ^ sx64;
#pragma unroll
        for (int nf = 0; nf < 4; ++nf) {
          bf16x8 bb = *(const bf16x8*)(xfb + nf * 16384 + off);
          acc[0][nf] = mfma16(c0a, bb, acc[0][nf]);
          acc[1][nf] = mfma16(c0b, bb, acc[1][nf]);
        }
        c0a = c1a; c0b = c1b; c1a = nna; c1b = nnb;
      }
      const float* bp = bp1 + h * 64;
#pragma unroll
      for (int mi = 0; mi < 2; ++mi) {
        const int db = p1_mh * 32 + mi * 16 + 4 * g4;
        const float4 bs = *(const float4*)(bp + db);
        const float ba[4] = { bs.x, bs.y, bs.z, bs.w };
#pragma unroll
        for (int nf = 0; nf < 4; ++nf) {
          s16x4 pk;
#pragma unroll
          for (int r = 0; r < 4; ++r) pk[r] = f2b(acc[mi][nf][r] + ba[r]);
          *(s16x4*)ksw(ob, nf * 16 + l16, 2 * db) = pk;   // khT/qhT [n][d]
        }
      }
    }
    __syncthreads();

    // Depth-2 V prefetch (hidden under P2)
    const short* wbv = Wv + (size_t)(g2 * 4 + p34_j) * 32768
                     + (p34_qr >> 1) * 16384 + (p34_qr & 1) * 512 + lane * 8;
    bf16x8 pv0 = *(const bf16x8*)(wbv);
    bf16x8 pv1 = *(const bf16x8*)(wbv + 1024);

    // ---- P2: S^T = Q.K^T + softmax over keys; w overlays qslot rows ----
    {
      char* gb = smem + SM_X + p2_j * SM_HD;
      short* kb  = (short*)gb;
      short* qb_ = (short*)(gb + 8192);
      f32x4 st[4] = {};
#pragma unroll
      for (int dk = 0; dk < 2; ++dk) {
        const int bo = dk * 64 + 16 * g4;
        bf16x8 a = *(const bf16x8*)ksw(qb_, p2_qb + l16, bo);
#pragma unroll
        for (int tt = 0; tt < 4; ++tt) {
          bf16x8 bb = *(const bf16x8*)ksw(kb, tt * 16 + l16, bo);
          st[tt] = mfma16(a, bb, st[tt]);   // st[tt][r]=S[q=qb+4g4+r][key=16tt+l16]
        }
      }
      const float scale = 0.044194173824159216f;   // 1/sqrt(512)
      float v[4][4], mx[4], sm[4];
#pragma unroll
      for (int tt = 0; tt < 4; ++tt) {
        const float pen = mrow[tt * 16 + l16];
#pragma unroll
        for (int r = 0; r < 4; ++r) v[tt][r] = st[tt][r] * scale - pen;
      }
#pragma unroll
      for (int r = 0; r < 4; ++r)
        mx[r] = fmaxf(fmaxf(v[0][r], v[1][r]), fmaxf(v[2][r], v[3][r]));
#pragma unroll
      for (int d = 1; d <= 8; d <<= 1)
#pragma unroll
        for (int r = 0; r < 4; ++r) mx[r] = fmaxf(mx[r], __shfl_xor(mx[r], d));
#pragma unroll
      for (int r = 0; r < 4; ++r) sm[r] = 0.f;
#pragma unroll
      for (int tt = 0; tt < 4; ++tt)
#pragma unroll
        for (int r = 0; r < 4; ++r) { v[tt][r] = __expf(v[tt][r] - mx[r]); sm[r] += v[tt][r]; }
#pragma unroll
      for (int d = 1; d <= 8; d <<= 1)
#pragma unroll
        for (int r = 0; r < 4; ++r) sm[r] += __shfl_xor(sm[r], d);
#pragma unroll
      for (int r = 0; r < 4; ++r) sm[r] = 1.0f / sm[r];
#pragma unroll
      for (int tt = 0; tt < 4; ++tt)
#pragma unroll
        for (int r = 0; r < 4; ++r)
          *(short*)ksw(qb_, p2_qb + 4 * g4 + r, 2 * (tt * 16 + l16)) =
              f2b(v[tt][r] * sm[r]);   // w[q][key]
    }
    __syncthreads();

    // ---- P3: V projection (quarter-head per wave), depth-2; V overlays kslot ----
    {
      char* gb = smem + SM_X + p34_j * SM_HD;
      short* vbuf = (short*)gb;
      f32x4 acc[4] = {};
      bf16x8 c0 = pv0, c1 = pv1;
#pragma unroll
      for (int kk = 0; kk < 16; ++kk) {
        bf16x8 nn = c1;
        if (kk < 14) nn = *(const bf16x8*)(wbv + (kk + 2) * 1024);
        const int off = (kk * 64) ^ sx64;
#pragma unroll
        for (int nf = 0; nf < 4; ++nf) {
          bf16x8 bb = *(const bf16x8*)(xfb + nf * 16384 + off);
          acc[nf] = mfma16(c0, bb, acc[nf]);
        }
        c0 = c1; c1 = nn;
      }
      const int db = p34_qr * 16 + 4 * g4;
      const float4 bs = *(const float4*)(bv + (g2 * 4 + p34_j) * 64 + db);
      const float ba[4] = { bs.x, bs.y, bs.z, bs.w };
#pragma unroll
      for (int nf = 0; nf < 4; ++nf)
#pragma unroll
        for (int r = 0; r < 4; ++r)
          *(short*)ksw(vbuf, db + r, 2 * (nf * 16 + l16)) = f2b(acc[nf][r] + ba[r]);
    }
    __syncthreads();

    // ---- P4: O[d][q] = sum_key V[d][key]*w[q][key]; residual from LDS ----
    {
      const int h = g2 * 4 + p34_j;
      char* gb = smem + SM_X + p34_j * SM_HD;
      short* vbuf = (short*)gb;
      short* wbuf = (short*)(gb + 8192);
      f32x4 acc[4] = {};
#pragma unroll
      for (int dk = 0; dk < 2; ++dk) {
        const int bo = dk * 64 + 16 * g4;
        bf16x8 bw = *(const bf16x8*)ksw(wbuf, p34_qr * 16 + l16, bo);  // w rows q
#pragma unroll
        for (int nf = 0; nf < 4; ++nf) {
          bf16x8 av = *(const bf16x8*)ksw(vbuf, nf * 16 + l16, bo);    // V rows d
          acc[nf] = mfma16(av, bw, acc[nf]);   // acc[nf][r]=O[d=nf*16+4g4+r][q=qb+l16]
        }
      }
      const int q = p34_qr * 16 + l16;
      const size_t rowg = (PASS == 0) ? (size_t)((b * 64 + rc) * 64 + q)
                                      : (size_t)((b * 64 + q) * 64 + rc);
      char* grow = (char*)xw + rowg * 1024;
      const char* lrow = smem + q * 1024;
#pragma unroll
      for (int nf = 0; nf < 4; ++nf) {
        const int cb = (h * 128 + nf * 32 + 8 * g4) ^ sxl;
        const s16x4 rx = *(const s16x4*)(lrow + cb);
        if (FINAL) {
#pragma unroll
          for (int r = 0; r < 4; ++r) {
            const int ch = 8 * (nf * 16 + 4 * g4 + r) + h;
            const size_t off = (size_t)b * 2097152 + (size_t)ch * 4096
                             + ((PASS == 0) ? rc * 64 + q : q * 64 + rc);
            outp[off] = acc[nf][r] + b2f(rx[r]);
          }
        } else {
          s16x4 ov;
#pragma unroll
          for (int r = 0; r < 4; ++r) ov[r] = f2b(acc[nf][r] + b2f(rx[r]));
          *(s16x4*)(grow + cb) = ov;
        }
      }
      if (g2 == 0) {   // depth-2 prefetch of iter-1 K/Q (drained by barrier)
        const short* wb2 = wb_nh + (4 + p1_j) * 32768;
        pa0 = *(const bf16x8*)(wb2);
        pa1 = *(const bf16x8*)(wb2 + 512);
        pa2 = *(const bf16x8*)(wb2 + 1024);
        pa3 = *(const bf16x8*)(wb2 + 1536);
      }
    }
    __syncthreads();
  }
}

// x[b][ch][nr][nc] f32 -> xw[b][nr][nc][p] bf16 pre-swizzled.
__global__ __launch_bounds__(256)
void prep_x(const float* __restrict__ x, unsigned short* __restrict__ xw)
{
  extern __shared__ float tile[];            // [64][521]
  const int b = blockIdx.x >> 6, nr = blockIdx.x & 63;
  const float* src = x + (size_t)b * 2097152 + nr * 64;
  const int t = threadIdx.x;
#pragma unroll 4
  for (int it = 0; it < 32; ++it) {
    const int idx = it * 256 + t;
    const int ch = idx >> 4, nc4 = (idx & 15) * 4;
    const float4 v = *(const float4*)(src + (size_t)ch * 4096 + nc4);
    const int p = ((ch & 7) << 6) | (ch >> 3);
    const int pp = p + (p >> 6);
    tile[(nc4 + 0) * 521 + pp] = v.x;
    tile[(nc4 + 1) * 521 + pp] = v.y;
    tile[(nc4 + 2) * 521 + pp] = v.z;
    tile[(nc4 + 3) * 521 + pp] = v.w;
  }
  __syncthreads();
  unsigned short* dst = xw + (size_t)(b * 64 + nr) * 32768;
#pragma unroll 4
  for (int it = 0; it < 16; ++it) {
    const int idx = it * 256 + t;
    const int nc = idx >> 6, p8 = (idx & 63) * 8;
    bf16x8 o;
#pragma unroll
    for (int j = 0; j < 8; ++j) {
      const int p = p8 + j;
      o[j] = f2b(tile[nc * 521 + p + (p >> 6)]);
    }
    const int sx = ((nr ^ nc) & 7) << 4;
    *(bf16x8*)((char*)(dst + nc * 512) + ((2 * p8) ^ sx)) = o;
  }
}

// Fallback un-permute of one b-slab: tmp[nr][nc][p] bf16 swz -> out[ch][nr][nc] f32
__global__ __launch_bounds__(256)
void unperm_b(const unsigned short* __restrict__ tmp, float* __restrict__ out)
{
  __shared__ float tile[64 * 65];
  const int nr = blockIdx.x >> 3, pb = blockIdx.x & 7;
  const int t = threadIdx.x;
#pragma unroll
  for (int it = 0; it < 4; ++it) {
    const int idx = it * 256 + t;
    const int nc = idx >> 4, p4 = (idx & 15) * 4;
    const int sx = ((nr ^ nc) & 7) << 4;
    const s16x4 v = *(const s16x4*)((const char*)(tmp + ((size_t)nr * 64 + nc) * 512)
                                    + ((2 * (pb * 64 + p4)) ^ sx));
#pragma unroll
    for (int j = 0; j < 4; ++j) tile[nc * 65 + p4 + j] = b2f(v[j]);
  }
  __syncthreads();
#pragma unroll
  for (int it = 0; it < 4; ++it) {
    const int idx = it * 256 + t;
    const int pi = idx >> 4, nc4 = (idx & 15) * 4;
    const int ch = 8 * pi + pb;
    float4 o;
#pragma unroll
    for (int j = 0; j < 4; ++j) (&o.x)[j] = tile[(nc4 + j) * 65 + pi];
    *(float4*)(out + (size_t)ch * 4096 + nr * 64 + nc4) = o;
  }
}

// Weights [3][512][512] f32 -> fragment order with k-elements in p-order (as R5).
__global__ void pack_w(const float* __restrict__ w0, const float* __restrict__ w1,
                       const float* __restrict__ w2, const float* __restrict__ w3,
                       const float* __restrict__ w4, const float* __restrict__ w5,
                       short* __restrict__ dst)
{
  const float* s;
  switch (blockIdx.y) {
    case 0: s = w0; break; case 1: s = w1; break; case 2: s = w2; break;
    case 3: s = w3; break; case 4: s = w4; break; default: s = w5; break;
  }
  const int idx = blockIdx.x * 256 + threadIdx.x;   // 0 .. 196607
  const int l = idx >> 16;
  const int r = idx & 65535;
  const int o = r >> 7, c4 = (r & 127) * 4;
  const float4 v = *(const float4*)(s + ((size_t)l * 512 + o) * 512 + c4);
  const int h = o & 7, row8 = o >> 3;
  const int mh = row8 >> 5, f = (row8 >> 4) & 1, l16r = row8 & 15;
  short* db = dst + (size_t)blockIdx.y * 786432 + (size_t)l * 262144;
#pragma unroll
  for (int j = 0; j < 4; ++j) {
    const int ch = c4 + j;
    const int p = ((ch & 7) << 6) | (ch >> 3);
    const int jj = p & 7, g4p = (p >> 3) & 3, kk = p >> 5;
    const int lane = g4p * 16 + l16r;
    db[(size_t)(((((h * 2 + mh) * 16 + kk) * 2 + f) * 64 + lane)) * 8 + jj] =
        f2b((&v.x)[j]);
  }
}

// Biases [3][512] f32 -> [name][l][h][64] f32
__global__ void pack_b(const float* __restrict__ b0, const float* __restrict__ b1,
                       const float* __restrict__ b2, const float* __restrict__ b3,
                       const float* __restrict__ b4, const float* __restrict__ b5,
                       float* __restrict__ dst)
{
  const int idx = blockIdx.x * 256 + threadIdx.x;   // 0..9215
  const int name = idx / 1536;
  const int rem  = idx - name * 1536;
  const int l = rem >> 9;
  const int p = rem & 511;
  const int h = p >> 6, d = p & 63;
  const float* s;
  switch (name) {
    case 0: s = b0; break; case 1: s = b1; break; case 2: s = b2; break;
    case 3: s = b3; break; case 4: s = b4; break; default: s = b5; break;
  }
  dst[idx] = s[l * 512 + 8 * d + h];
}

__global__ void copy_masks(const float* __restrict__ m, float* __restrict__ o) {
  const int i = blockIdx.x * 256 + threadIdx.x;
  ((float4*)o)[i] = ((const float4*)m)[i];
}

extern "C" void kernel_launch(void* const* d_in, const int* in_sizes, int n_in,
                              void* d_out, int out_size, void* d_ws, size_t ws_size,
                              hipStream_t stream)
{
  const float* x0    = (const float*)d_in[0];
  const float* masks = (const float*)d_in[1];
  short* wbf  = (short*)d_ws;                        // packed weights, 9.44 MB
  float* bws  = (float*)((char*)d_ws + 9437184);     // packed biases, 36.9 KB
  float* xbuf = (float*)d_out;
  float* mout = xbuf + 16777216;

  const size_t xw_off = 9474048;                     // after weights + biases
  const bool big = ws_size >= xw_off + (size_t)33554432;   // xw bf16 = 32 MB
  unsigned short* xw = big ? (unsigned short*)((char*)d_ws + xw_off)
                           : (unsigned short*)d_out;

  pack_w<<<dim3(768, 6), 256, 0, stream>>>(
      (const float*)d_in[2], (const float*)d_in[3], (const float*)d_in[4],
      (const float*)d_in[5], (const float*)d_in[6], (const float*)d_in[7], wbf);
  pack_b<<<36, 256, 0, stream>>>(
      (const float*)d_in[8], (const float*)d_in[9], (const float*)d_in[10],
      (const float*)d_in[11], (const float*)d_in[12], (const float*)d_in[13], bws);
  prep_x<<<512, 256, 64 * 521 * 4, stream>>>(x0, xw);
  copy_masks<<<32, 256, 0, stream>>>(masks, mout);

  const size_t WPL = 262144;
  for (int l = 0; l < 3; ++l) {
    attn_pass<0, 0><<<512, 1024, SM_TOTAL, stream>>>(
        xw, xbuf,
        wbf + (0 * 3 + l) * WPL, wbf + (1 * 3 + l) * WPL, wbf + (2 * 3 + l) * WPL,
        bws + (0 * 3 + l) * 512, bws + (1 * 3 + l) * 512, bws + (2 * 3 + l) * 512,
        masks);
    const short* rwk = wbf + (3 * 3 + l) * WPL;
    const short* rwq = wbf + (4 * 3 + l) * WPL;
    const short* rwv = wbf + (5 * 3 + l) * WPL;
    const float* rbk = bws + (3 * 3 + l) * 512;
    const float* rbq = bws + (4 * 3 + l) * 512;
    const float* rbv = bws + (5 * 3 + l) * 512;
    if (l == 2 && big)
      attn_pass<1, 1><<<512, 1024, SM_TOTAL, stream>>>(
          xw, xbuf, rwk, rwq, rwv, rbk, rbq, rbv, masks);
    else
      attn_pass<1, 0><<<512, 1024, SM_TOTAL, stream>>>(
          xw, xbuf, rwk, rwq, rwv, rbk, rbq, rbv, masks);
  }

  if (!big) {
    // xw (bf16, 32MB) aliases the front of d_out; un-permute per b-slab via a
    // ws bounce, in REVERSE order so out-writes never clobber unread slabs.
    for (int b = 7; b >= 0; --b) {
      hipMemcpyAsync(wbf, xw + (size_t)b * 2097152, 4194304,
                     hipMemcpyDeviceToDevice, stream);
      unperm_b<<<512, 256, 0, stream>>>((const unsigned short*)wbf,
                                        xbuf + (size_t)b * 2097152);
    }
  }
}